// Round 6
// baseline (284.390 us; speedup 1.0000x reference)
//
#include <hip/hip_runtime.h>

#define NROWS    2097152
#define W        16
#define NTHREADS 256
#define NBLK     (NROWS / NTHREADS)   // 8192 blocks, exactly 1 row per thread

typedef float f4 __attribute__((ext_vector_type(4)));

__global__ __launch_bounds__(256) void cel_weight_kernel(
    const float* __restrict__ predict,
    const float* __restrict__ target,
    const float* __restrict__ penalty,
    float* __restrict__ partials)
{
    __shared__ float s_pen[W * W];
    __shared__ float s_part[4];

    const int tid = threadIdx.x;
    s_pen[tid] = penalty[tid];                 // blockDim == 256 == W*W
    __syncthreads();

    // XCD-contiguous swizzle: dispatch assigns block b to XCD b%8 (round-robin),
    // so give XCD x the contiguous x-th eighth of the row space. Locality only —
    // correctness does not depend on the mapping.
    const int bid = (int)blockIdx.x;
    const int sw  = (bid & 7) * (NBLK / 8) + (bid >> 3);
    const int row = sw * NTHREADS + tid;

    const f4* prow = (const f4*)(predict + (size_t)row * W);
    const f4* trow = (const f4*)(target  + (size_t)row * W);

    // 8 independent non-temporal 16B loads, all issued before any use.
    f4 p0 = __builtin_nontemporal_load(prow + 0);
    f4 p1 = __builtin_nontemporal_load(prow + 1);
    f4 p2 = __builtin_nontemporal_load(prow + 2);
    f4 p3 = __builtin_nontemporal_load(prow + 3);
    f4 t0 = __builtin_nontemporal_load(trow + 0);
    f4 t1 = __builtin_nontemporal_load(trow + 1);
    f4 t2 = __builtin_nontemporal_load(trow + 2);
    f4 t3 = __builtin_nontemporal_load(trow + 3);

    float pv[W] = {p0.x, p0.y, p0.z, p0.w, p1.x, p1.y, p1.z, p1.w,
                   p2.x, p2.y, p2.z, p2.w, p3.x, p3.y, p3.z, p3.w};
    float tv[W] = {t0.x, t0.y, t0.z, t0.w, t1.x, t1.y, t1.z, t1.w,
                   t2.x, t2.y, t2.z, t2.w, t3.x, t3.y, t3.z, t3.w};

    // argmax(predict), first-index tie-break (matches jnp.argmax)
    float pmax = pv[0]; int pidx = 0;
    #pragma unroll
    for (int j = 1; j < W; ++j)
        if (pv[j] > pmax) { pmax = pv[j]; pidx = j; }

    // softmax denominator; numerator at argmax is exp(0)=1
    float s = 0.0f;
    #pragma unroll
    for (int j = 0; j < W; ++j) s += __expf(pv[j] - pmax);

    // argmax(target)
    float tmax = tv[0]; int tidx = 0;
    #pragma unroll
    for (int j = 1; j < W; ++j)
        if (tv[j] > tmax) { tmax = tv[j]; tidx = j; }

    float wgt = (pidx == tidx) ? 0.0f : s_pen[tidx * W + pidx];
    float acc = wgt / s;

    // wave-64 reduction → per-block partial (no atomics)
    #pragma unroll
    for (int off = 32; off > 0; off >>= 1)
        acc += __shfl_down(acc, off);

    const int lane = tid & 63;
    const int wid  = tid >> 6;
    if (lane == 0) s_part[wid] = acc;
    __syncthreads();
    if (tid == 0)
        partials[bid] = s_part[0] + s_part[1] + s_part[2] + s_part[3];
}

__global__ __launch_bounds__(256) void reduce_kernel(
    const float* __restrict__ partials, float* __restrict__ out)
{
    __shared__ float sp[4];
    const int tid = threadIdx.x;
    float a = 0.0f;
    #pragma unroll
    for (int i = 0; i < NBLK / NTHREADS; ++i)
        a += partials[tid + i * NTHREADS];
    #pragma unroll
    for (int off = 32; off > 0; off >>= 1)
        a += __shfl_down(a, off);
    if ((tid & 63) == 0) sp[tid >> 6] = a;
    __syncthreads();
    if (tid == 0)
        out[0] = (sp[0] + sp[1] + sp[2] + sp[3]) * (1.0f / (float)NROWS);
}

extern "C" void kernel_launch(void* const* d_in, const int* in_sizes, int n_in,
                              void* d_out, int out_size, void* d_ws, size_t ws_size,
                              hipStream_t stream)
{
    const float* predict = (const float*)d_in[0];
    const float* target  = (const float*)d_in[1];
    const float* penalty = (const float*)d_in[2];
    float* out      = (float*)d_out;
    float* partials = (float*)d_ws;   // NBLK floats, fully overwritten each call

    cel_weight_kernel<<<dim3(NBLK), dim3(NTHREADS), 0, stream>>>(
        predict, target, penalty, partials);
    reduce_kernel<<<dim3(1), dim3(NTHREADS), 0, stream>>>(partials, out);
}